// Round 18
// baseline (377.564 us; speedup 1.0000x reference)
//
#include <hip/hip_runtime.h>
#include <hip/hip_bf16.h>

constexpr int F_IN  = 512;
constexpr int HID   = 16;
constexpr int NCLS  = 40;
constexpr int CHUNK = 4096;   // edges per chunk
constexpr int BMAX  = 800;    // max buckets (N=100000 -> NB=782)
constexpr int SMAX  = 6144;   // max edges per bucket

typedef float f4v __attribute__((ext_vector_type(4)));

// packed edge: (src << 15) | (bf16(ew) & 0x7fff)  -- ew >= 0 so sign bit free
__device__ __forceinline__ unsigned packEdge(int s, float w) {
  __hip_bfloat16 h = __float2bfloat16(w);
  unsigned short hb = *reinterpret_cast<unsigned short*>(&h);
  return ((unsigned)s << 15) | (unsigned)(hb & 0x7fff);
}
__device__ __forceinline__ float edgeW(unsigned p) {
  return __uint_as_float((p & 0x7fffu) << 16);
}

// ---- zero the scan pad [lo,hi) of counts ----
__global__ void k_zpad(int* __restrict__ counts, int lo, int hi) {
  int i = lo + blockIdx.x * 256 + threadIdx.x;
  if (i < hi) counts[i] = 0;
}

// ---- scan over counts (bucket-major), 3 stages, in-place ----
__global__ void k_scanA(const int* __restrict__ a, int* __restrict__ bsum) {
  __shared__ int sd[256];
  int t = threadIdx.x;
  int4 v = reinterpret_cast<const int4*>(a)[blockIdx.x * 256 + t];
  sd[t] = v.x + v.y + v.z + v.w;
  __syncthreads();
  for (int off = 128; off > 0; off >>= 1) {
    if (t < off) sd[t] += sd[t + off];
    __syncthreads();
  }
  if (!t) bsum[blockIdx.x] = sd[0];
}

__global__ void k_scanB(int* __restrict__ bsum, int nb) {
  __shared__ int sd[1024];
  int t = threadIdx.x;
  int v = (t < nb) ? bsum[t] : 0;
  sd[t] = v;
  __syncthreads();
  for (int off = 1; off < 1024; off <<= 1) {
    int add = (t >= off) ? sd[t - off] : 0;
    __syncthreads();
    sd[t] += add;
    __syncthreads();
  }
  if (t < nb) bsum[t] = sd[t] - v;  // exclusive
}

__global__ void k_scanC(int* __restrict__ a, const int* __restrict__ bsum) {
  __shared__ int sd[256];
  int t = threadIdx.x;
  int4 v = reinterpret_cast<int4*>(a)[blockIdx.x * 256 + t];
  int ts = v.x + v.y + v.z + v.w;
  sd[t] = ts;
  __syncthreads();
  for (int off = 1; off < 256; off <<= 1) {
    int add = (t >= off) ? sd[t - off] : 0;
    __syncthreads();
    sd[t] += add;
    __syncthreads();
  }
  int pre = bsum[blockIdx.x] + sd[t] - ts;
  int4 w;
  w.x = pre; w.y = pre + v.x; w.z = w.y + v.y; w.w = w.z + v.z;
  reinterpret_cast<int4*>(a)[blockIdx.x * 256 + t] = w;
}

// ---- Pass B: chunk-local LDS counting sort by bucket; STREAMING writes.
//      Emits packed u32 payload + parallel dst-low7 byte array + counts. ----
__global__ void __launch_bounds__(256)
k_scat2(const int* __restrict__ src, const int* __restrict__ dst,
        const float* __restrict__ ew, unsigned* __restrict__ payloadA,
        unsigned char* __restrict__ dlowA, int* __restrict__ segs,
        int* __restrict__ counts, int E, int NB, int NBLK) {
  __shared__ unsigned ebuf32[CHUNK];       // 16 KB
  __shared__ unsigned char ebufd[CHUNK];   // 4 KB
  __shared__ int hist[1024];
  __shared__ int sc[256];
  int t = threadIdx.x;
  int c = blockIdx.x;
  int cbase = c * CHUNK;
  int sz = min(CHUNK, E - cbase);
#pragma unroll
  for (int i = 0; i < 4; ++i) hist[t + 256 * i] = 0;
  __syncthreads();
  unsigned pk[16];
  unsigned char dl[16];
  int key[16];
#pragma unroll
  for (int r = 0; r < 16; ++r) {
    int i = r * 256 + t;
    int e = cbase + i;
    if (i < sz) {
      int s = src[e], d = dst[e];
      pk[r] = packEdge(s, ew[e]);
      dl[r] = (unsigned char)(d & 127);
      key[r] = d >> 7;
      atomicAdd(&hist[key[r]], 1);
    } else {
      key[r] = -1;
    }
  }
  __syncthreads();
  int h0 = hist[4 * t], h1 = hist[4 * t + 1], h2 = hist[4 * t + 2], h3 = hist[4 * t + 3];
  int tsum = h0 + h1 + h2 + h3;
  sc[t] = tsum;
  __syncthreads();
  for (int off = 1; off < 256; off <<= 1) {
    int add = (t >= off) ? sc[t - off] : 0;
    __syncthreads();
    sc[t] += add;
    __syncthreads();
  }
  int pre = sc[t] - tsum;
  __syncthreads();
  hist[4 * t]     = pre;
  hist[4 * t + 1] = pre + h0;
  hist[4 * t + 2] = pre + h0 + h1;
  hist[4 * t + 3] = pre + h0 + h1 + h2;
  __syncthreads();
  size_t sb = (size_t)c * (NB + 1);
  for (int b = t; b < NB; b += 256) {
    int lo = hist[b];
    segs[sb + b] = lo;
    counts[b * NBLK + c] = hist[b + 1] - lo;
  }
  if (t == 0) segs[sb + NB] = sz;
  __syncthreads();
#pragma unroll
  for (int r = 0; r < 16; ++r) {
    if (key[r] >= 0) {
      int pos = atomicAdd(&hist[key[r]], 1);
      ebuf32[pos] = pk[r];
      ebufd[pos]  = dl[r];
    }
  }
  __syncthreads();
  for (int i = t; i < sz; i += 256) {
    payloadA[cbase + i] = ebuf32[i];
    dlowA[cbase + i]    = ebufd[i];
  }
}

// ---- Pass C: per-bucket assembly + node counting sort; streaming writes ----
__global__ void __launch_bounds__(256)
k_sortb2(const unsigned* __restrict__ payloadA, const unsigned char* __restrict__ dlowA,
         const int* __restrict__ segs, const int* __restrict__ cnts,
         unsigned* __restrict__ payloadB, int* __restrict__ rs,
         float* __restrict__ dis, int N, int NB, int NBLK) {
  __shared__ unsigned ebuf32[SMAX];        // 24 KB
  __shared__ unsigned char ebufd[SMAX];    // 6 KB
  __shared__ int hcnt[128];
  __shared__ int scn[128];
  __shared__ float dgs[128];
  int t = threadIdx.x;
  int b = blockIdx.x;
  if (t < 128) { hcnt[t] = 0; dgs[t] = 1.0f; }
  __syncthreads();
  int beg = cnts[b * NBLK];
  int end = cnts[b * NBLK + NBLK];
  for (int c = t; c < NBLK; c += 256) {
    int rel = cnts[b * NBLK + c] - beg;
    size_t sb = (size_t)c * (NB + 1) + b;
    int s0 = segs[sb], s1 = segs[sb + 1];
    int gsrc = c * CHUNK + s0;
    for (int k = 0; k < s1 - s0; ++k) {
      unsigned p = payloadA[gsrc + k];
      unsigned char d8 = dlowA[gsrc + k];
      ebuf32[rel + k] = p;
      ebufd[rel + k]  = d8;
      atomicAdd(&hcnt[d8], 1);
      atomicAdd(&dgs[d8], edgeW(p));
    }
  }
  __syncthreads();
  int v = (t < 128) ? hcnt[t] : 0;
  if (t < 128) scn[t] = v;
  __syncthreads();
  for (int off = 1; off < 128; off <<= 1) {
    int add = (t < 128 && t >= off) ? scn[t - off] : 0;
    __syncthreads();
    if (t < 128) scn[t] += add;
    __syncthreads();
  }
  int base = b * 128;
  if (t < 128) {
    int st = scn[t] - v;
    hcnt[t] = st;
    rs[base + t] = beg + st;
    int n = base + t;
    if (n < N) dis[n] = rsqrtf(dgs[t]);
  }
  if (t == 0) rs[base + 128] = end;
  __syncthreads();
  int sz = end - beg;
  for (int i = t; i < sz; i += 256) {
    int pos = beg + atomicAdd(&hcnt[ebufd[i]], 1);
    payloadB[pos] = ebuf32[i];
  }
}

__device__ __forceinline__ float blo(unsigned u) { return __uint_as_float(u << 16); }
__device__ __forceinline__ float bhi(unsigned u) { return __uint_as_float(u & 0xffff0000u); }
__device__ __forceinline__ unsigned pack2(float lo, float hi) {
  __hip_bfloat16 l = __float2bfloat16(lo), h = __float2bfloat16(hi);
  unsigned short ul = *reinterpret_cast<unsigned short*>(&l);
  unsigned short uh = *reinterpret_cast<unsigned short*>(&h);
  return (unsigned)ul | ((unsigned)uh << 16);
}

// ---- h1' = (x @ W1) * dis : thread = row x K-quarter, NONTEMPORAL x loads
//      (bypass L1 allocation -> no thrash at 24 waves/CU; lines stream via L2).
//      k wave-uniform -> W1 via s_load. Combine via stride-17 LDS. ----
__global__ void __launch_bounds__(256)
k_gemm1g(const float* __restrict__ x, const float* __restrict__ W1,
         const float* __restrict__ dis, uint4* __restrict__ hb1, int N) {
  __shared__ float ps[4 * 64 * 17];   // 17.4 KB
  int t = threadIdx.x;
  int r = t & 63, s = t >> 6;
  int nb = blockIdx.x * 64;
  int n = nb + r;
  float acc[HID];
#pragma unroll
  for (int j = 0; j < HID; ++j) acc[j] = 0.0f;
  if (n < N) {
    const f4v* xr = reinterpret_cast<const f4v*>(x + (size_t)n * F_IN + s * 128);
    const float* wp = W1 + (size_t)(s * 128) * HID;
#pragma unroll 8
    for (int c = 0; c < 32; ++c) {            // 32 x float4 = 128 floats
      f4v v = __builtin_nontemporal_load(xr + c);
      const float* wr = wp + (c * 4) * HID;
#pragma unroll
      for (int j = 0; j < HID; ++j) {
        acc[j] = fmaf(v.x, wr[j], acc[j]);
        acc[j] = fmaf(v.y, wr[HID + j], acc[j]);
        acc[j] = fmaf(v.z, wr[2 * HID + j], acc[j]);
        acc[j] = fmaf(v.w, wr[3 * HID + j], acc[j]);
      }
    }
  }
#pragma unroll
  for (int j = 0; j < HID; ++j) ps[(s * 64 + r) * 17 + j] = acc[j];
  __syncthreads();
  if (t < 64) {
    if (n < N) {
      float di = dis[n];
      float o[HID];
#pragma unroll
      for (int j = 0; j < HID; ++j)
        o[j] = (ps[t * 17 + j] + ps[(64 + t) * 17 + j] +
                ps[(128 + t) * 17 + j] + ps[(192 + t) * 17 + j]) * di;
      uint4 w0, w1;
      w0.x = pack2(o[0],  o[1]);  w0.y = pack2(o[2],  o[3]);
      w0.z = pack2(o[4],  o[5]);  w0.w = pack2(o[6],  o[7]);
      w1.x = pack2(o[8],  o[9]);  w1.y = pack2(o[10], o[11]);
      w1.z = pack2(o[12], o[13]); w1.w = pack2(o[14], o[15]);
      hb1[(size_t)n * 2]     = w0;
      hb1[(size_t)n * 2 + 1] = w1;
    }
  }
}

// ---- aggregation: FOUR LANES PER NODE, packed 4B edges, shfl combine.
//      LAYER1: hb2 = bf16(relu((acc+self)*dis+b1)*dis)
//      LAYER2: fused 16->40 GEMM + log_softmax (lane q: classes [10q,10q+10)) ----
template <int LAYER>
__global__ void __launch_bounds__(256)
k_aggn4(const unsigned* __restrict__ payload, const int* __restrict__ rs,
        const uint4* __restrict__ hb, const float* __restrict__ dis,
        const float* __restrict__ b1, uint4* __restrict__ hb2,
        const float* __restrict__ W2, const float* __restrict__ b2,
        float* __restrict__ out, int N) {
  int tid = blockIdx.x * 256 + threadIdx.x;
  int n = tid >> 2;
  int q = tid & 3;
  if (n >= N) return;
  int e0 = rs[n], e1 = rs[n + 1];
  float a0 = 0, a1 = 0, a2 = 0, a3 = 0, a4 = 0, a5 = 0, a6 = 0, a7 = 0;
  float a8 = 0, a9 = 0, a10 = 0, a11 = 0, a12 = 0, a13 = 0, a14 = 0, a15 = 0;
  for (int e = e0 + q; e < e1; e += 4) {
    unsigned p = payload[e];
    const uint4* row = hb + ((size_t)(p >> 15) * 2);
    uint4 r0 = row[0];
    uint4 r1 = row[1];
    float w = edgeW(p);
    a0  = fmaf(blo(r0.x), w, a0);  a1  = fmaf(bhi(r0.x), w, a1);
    a2  = fmaf(blo(r0.y), w, a2);  a3  = fmaf(bhi(r0.y), w, a3);
    a4  = fmaf(blo(r0.z), w, a4);  a5  = fmaf(bhi(r0.z), w, a5);
    a6  = fmaf(blo(r0.w), w, a6);  a7  = fmaf(bhi(r0.w), w, a7);
    a8  = fmaf(blo(r1.x), w, a8);  a9  = fmaf(bhi(r1.x), w, a9);
    a10 = fmaf(blo(r1.y), w, a10); a11 = fmaf(bhi(r1.y), w, a11);
    a12 = fmaf(blo(r1.z), w, a12); a13 = fmaf(bhi(r1.z), w, a13);
    a14 = fmaf(blo(r1.w), w, a14); a15 = fmaf(bhi(r1.w), w, a15);
  }
#pragma unroll
  for (int m = 1; m <= 2; m <<= 1) {
    a0  += __shfl_xor(a0,  m); a1  += __shfl_xor(a1,  m);
    a2  += __shfl_xor(a2,  m); a3  += __shfl_xor(a3,  m);
    a4  += __shfl_xor(a4,  m); a5  += __shfl_xor(a5,  m);
    a6  += __shfl_xor(a6,  m); a7  += __shfl_xor(a7,  m);
    a8  += __shfl_xor(a8,  m); a9  += __shfl_xor(a9,  m);
    a10 += __shfl_xor(a10, m); a11 += __shfl_xor(a11, m);
    a12 += __shfl_xor(a12, m); a13 += __shfl_xor(a13, m);
    a14 += __shfl_xor(a14, m); a15 += __shfl_xor(a15, m);
  }
  uint4 s0 = hb[(size_t)n * 2];
  uint4 s1 = hb[(size_t)n * 2 + 1];
  float di = dis[n];
  a0  = (a0  + blo(s0.x)) * di;  a1  = (a1  + bhi(s0.x)) * di;
  a2  = (a2  + blo(s0.y)) * di;  a3  = (a3  + bhi(s0.y)) * di;
  a4  = (a4  + blo(s0.z)) * di;  a5  = (a5  + bhi(s0.z)) * di;
  a6  = (a6  + blo(s0.w)) * di;  a7  = (a7  + bhi(s0.w)) * di;
  a8  = (a8  + blo(s1.x)) * di;  a9  = (a9  + bhi(s1.x)) * di;
  a10 = (a10 + blo(s1.y)) * di;  a11 = (a11 + bhi(s1.y)) * di;
  a12 = (a12 + blo(s1.z)) * di;  a13 = (a13 + bhi(s1.z)) * di;
  a14 = (a14 + blo(s1.w)) * di;  a15 = (a15 + bhi(s1.w)) * di;
  if (LAYER == 1) {
    a0  = fmaxf(a0  + b1[0],  0.0f) * di;  a1  = fmaxf(a1  + b1[1],  0.0f) * di;
    a2  = fmaxf(a2  + b1[2],  0.0f) * di;  a3  = fmaxf(a3  + b1[3],  0.0f) * di;
    a4  = fmaxf(a4  + b1[4],  0.0f) * di;  a5  = fmaxf(a5  + b1[5],  0.0f) * di;
    a6  = fmaxf(a6  + b1[6],  0.0f) * di;  a7  = fmaxf(a7  + b1[7],  0.0f) * di;
    a8  = fmaxf(a8  + b1[8],  0.0f) * di;  a9  = fmaxf(a9  + b1[9],  0.0f) * di;
    a10 = fmaxf(a10 + b1[10], 0.0f) * di;  a11 = fmaxf(a11 + b1[11], 0.0f) * di;
    a12 = fmaxf(a12 + b1[12], 0.0f) * di;  a13 = fmaxf(a13 + b1[13], 0.0f) * di;
    a14 = fmaxf(a14 + b1[14], 0.0f) * di;  a15 = fmaxf(a15 + b1[15], 0.0f) * di;
    if (q == 0) {
      uint4 w0;
      w0.x = pack2(a0, a1);  w0.y = pack2(a2,  a3);
      w0.z = pack2(a4, a5);  w0.w = pack2(a6,  a7);
      hb2[(size_t)n * 2] = w0;
    } else if (q == 1) {
      uint4 w1;
      w1.x = pack2(a8,  a9);  w1.y = pack2(a10, a11);
      w1.z = pack2(a12, a13); w1.w = pack2(a14, a15);
      hb2[(size_t)n * 2 + 1] = w1;
    }
  } else {
    float gv[16] = {a0, a1, a2, a3, a4, a5, a6, a7,
                    a8, a9, a10, a11, a12, a13, a14, a15};
    float o[10];
#pragma unroll
    for (int cc = 0; cc < 10; ++cc) o[cc] = b2[q * 10 + cc];
#pragma unroll
    for (int j = 0; j < HID; ++j) {
      float gj = gv[j];
      const float* wr = W2 + j * NCLS + q * 10;
#pragma unroll
      for (int cc = 0; cc < 10; ++cc) o[cc] = fmaf(gj, wr[cc], o[cc]);
    }
    float m = o[0];
#pragma unroll
    for (int cc = 1; cc < 10; ++cc) m = fmaxf(m, o[cc]);
    m = fmaxf(m, __shfl_xor(m, 1));
    m = fmaxf(m, __shfl_xor(m, 2));
    float ss = 0.0f;
#pragma unroll
    for (int cc = 0; cc < 10; ++cc) ss += expf(o[cc] - m);
    ss += __shfl_xor(ss, 1);
    ss += __shfl_xor(ss, 2);
    float lse = m + logf(ss);
    float* orow = out + (size_t)n * NCLS + q * 10;
#pragma unroll
    for (int cc = 0; cc < 10; ++cc) orow[cc] = o[cc] - lse;
  }
}

extern "C" void kernel_launch(void* const* d_in, const int* in_sizes, int n_in,
                              void* d_out, int out_size, void* d_ws, size_t ws_size,
                              hipStream_t stream) {
  const float* x  = (const float*)d_in[0];
  const int*   ei = (const int*)d_in[1];
  const float* ew = (const float*)d_in[2];
  const float* W1 = (const float*)d_in[3];
  const float* b1 = (const float*)d_in[4];
  const float* W2 = (const float*)d_in[5];
  const float* b2 = (const float*)d_in[6];
  float* out = (float*)d_out;

  const int N = in_sizes[0] / F_IN;   // 100000
  const int E = in_sizes[2];          // 3200000
  const int* src = ei;
  const int* dst = ei + E;

  const int NB   = (N + 127) >> 7;             // 782 buckets
  const int NBLK = (E + CHUNK - 1) / CHUNK;    // 782 chunks
  const long long SCT = (long long)NB * NBLK + 1;
  const int Npad = (int)((SCT + 1023) & ~1023LL);
  const int nbScan = Npad / 1024;
  const int Nr   = (NB * 128 + 256 + 255) & ~255;
  const size_t SEGSZ = (size_t)NBLK * (NB + 1) + 4;

  // ws layout (4B words): counts[Npad] | bsum[1024] | dis[Nr] | rs[Nr] |
  //   hb1[N*8] | hb2[N*8] | payloadA[E] | dlowA[E/4] | segs[SEGSZ] | payloadB[E]
  int* counts = (int*)d_ws;
  int* bsum   = counts + Npad;
  float* dis  = (float*)(bsum + 1024);
  int* rs     = (int*)(dis + Nr);
  uint4* hb1  = (uint4*)(rs + Nr);
  uint4* hb2  = hb1 + (size_t)N * 2;
  unsigned* payloadA = (unsigned*)(hb2 + (size_t)N * 2);
  unsigned char* dlowA = (unsigned char*)(payloadA + (size_t)E);
  int* segs   = (int*)(dlowA + (((size_t)E + 3) & ~3ull));
  unsigned* payloadB = (unsigned*)(segs + SEGSZ);

  const int padLo = NB * NBLK;
  k_zpad<<<(Npad - padLo + 255) / 256, 256, 0, stream>>>(counts, padLo, Npad);
  k_scat2<<<NBLK, 256, 0, stream>>>(src, dst, ew, payloadA, dlowA, segs, counts, E, NB, NBLK);
  k_scanA<<<nbScan, 256, 0, stream>>>(counts, bsum);
  k_scanB<<<1, 1024, 0, stream>>>(bsum, nbScan);
  k_scanC<<<nbScan, 256, 0, stream>>>(counts, bsum);
  k_sortb2<<<NB, 256, 0, stream>>>(payloadA, dlowA, segs, counts, payloadB, rs, dis, N, NB, NBLK);
  k_gemm1g<<<(N + 63) / 64, 256, 0, stream>>>(x, W1, dis, hb1, N);
  const int gAgg = (N * 4 + 255) / 256;
  k_aggn4<1><<<gAgg, 256, 0, stream>>>(payloadB, rs, hb1, dis, b1, hb2,
                                       nullptr, nullptr, nullptr, N);
  k_aggn4<2><<<gAgg, 256, 0, stream>>>(payloadB, rs, hb2, dis, nullptr, nullptr,
                                       W2, b2, out, N);
}

// Round 19
// 204.750 us; speedup vs baseline: 1.8440x; 1.8440x over previous
//
#include <hip/hip_runtime.h>
#include <hip/hip_bf16.h>

constexpr int F_IN  = 512;
constexpr int HID   = 16;
constexpr int NCLS  = 40;
constexpr int CHUNK = 4096;   // edges per chunk
constexpr int BMAX  = 800;    // max buckets (N=100000 -> NB=782)
constexpr int SMAX  = 6144;   // max edges per bucket

// packed edge: (src << 15) | (bf16(ew) & 0x7fff)  -- ew >= 0 so sign bit free
__device__ __forceinline__ unsigned packEdge(int s, float w) {
  __hip_bfloat16 h = __float2bfloat16(w);
  unsigned short hb = *reinterpret_cast<unsigned short*>(&h);
  return ((unsigned)s << 15) | (unsigned)(hb & 0x7fff);
}
__device__ __forceinline__ float edgeW(unsigned p) {
  return __uint_as_float((p & 0x7fffu) << 16);
}

// ---- scan over counts (bucket-major), 3 stages, in-place.
//      Pad region [valid, Npad) is masked to 0 (no pre-zeroing needed);
//      the prefix written at index `valid` correctly equals E. ----
__global__ void k_scanA(const int* __restrict__ a, int* __restrict__ bsum, int valid) {
  __shared__ int sd[256];
  int t = threadIdx.x;
  int i4 = blockIdx.x * 256 + t;
  int4 v = reinterpret_cast<const int4*>(a)[i4];
  int base = i4 * 4;
  int s = ((base + 0 < valid) ? v.x : 0) + ((base + 1 < valid) ? v.y : 0) +
          ((base + 2 < valid) ? v.z : 0) + ((base + 3 < valid) ? v.w : 0);
  sd[t] = s; __syncthreads();
  for (int off = 128; off > 0; off >>= 1) {
    if (t < off) sd[t] += sd[t + off];
    __syncthreads();
  }
  if (!t) bsum[blockIdx.x] = sd[0];
}

__global__ void k_scanB(int* __restrict__ bsum, int nb) {
  __shared__ int sd[1024];
  int t = threadIdx.x;
  int v = (t < nb) ? bsum[t] : 0;
  sd[t] = v;
  __syncthreads();
  for (int off = 1; off < 1024; off <<= 1) {
    int add = (t >= off) ? sd[t - off] : 0;
    __syncthreads();
    sd[t] += add;
    __syncthreads();
  }
  if (t < nb) bsum[t] = sd[t] - v;  // exclusive
}

__global__ void k_scanC(int* __restrict__ a, const int* __restrict__ bsum, int valid) {
  __shared__ int sd[256];
  int t = threadIdx.x;
  int i4 = blockIdx.x * 256 + t;
  int4 v = reinterpret_cast<int4*>(a)[i4];
  int base = i4 * 4;
  int vx = (base + 0 < valid) ? v.x : 0;
  int vy = (base + 1 < valid) ? v.y : 0;
  int vz = (base + 2 < valid) ? v.z : 0;
  int vw = (base + 3 < valid) ? v.w : 0;
  int ts = vx + vy + vz + vw;
  sd[t] = ts;
  __syncthreads();
  for (int off = 1; off < 256; off <<= 1) {
    int add = (t >= off) ? sd[t - off] : 0;
    __syncthreads();
    sd[t] += add;
    __syncthreads();
  }
  int pre = bsum[blockIdx.x] + sd[t] - ts;
  int4 w;
  w.x = pre; w.y = pre + vx; w.z = w.y + vy; w.w = w.z + vz;
  reinterpret_cast<int4*>(a)[i4] = w;
}

// ---- Pass B: chunk-local LDS counting sort by bucket; STREAMING writes.
//      Emits packed u32 payload + parallel dst-low7 byte array + counts. ----
__global__ void __launch_bounds__(256)
k_scat2(const int* __restrict__ src, const int* __restrict__ dst,
        const float* __restrict__ ew, unsigned* __restrict__ payloadA,
        unsigned char* __restrict__ dlowA, int* __restrict__ segs,
        int* __restrict__ counts, int E, int NB, int NBLK) {
  __shared__ unsigned ebuf32[CHUNK];       // 16 KB
  __shared__ unsigned char ebufd[CHUNK];   // 4 KB
  __shared__ int hist[1024];
  __shared__ int sc[256];
  int t = threadIdx.x;
  int c = blockIdx.x;
  int cbase = c * CHUNK;
  int sz = min(CHUNK, E - cbase);
#pragma unroll
  for (int i = 0; i < 4; ++i) hist[t + 256 * i] = 0;
  __syncthreads();
  unsigned pk[16];
  unsigned char dl[16];
  int key[16];
#pragma unroll
  for (int r = 0; r < 16; ++r) {
    int i = r * 256 + t;
    int e = cbase + i;
    if (i < sz) {
      int s = src[e], d = dst[e];
      pk[r] = packEdge(s, ew[e]);
      dl[r] = (unsigned char)(d & 127);
      key[r] = d >> 7;
      atomicAdd(&hist[key[r]], 1);
    } else {
      key[r] = -1;
    }
  }
  __syncthreads();
  int h0 = hist[4 * t], h1 = hist[4 * t + 1], h2 = hist[4 * t + 2], h3 = hist[4 * t + 3];
  int tsum = h0 + h1 + h2 + h3;
  sc[t] = tsum;
  __syncthreads();
  for (int off = 1; off < 256; off <<= 1) {
    int add = (t >= off) ? sc[t - off] : 0;
    __syncthreads();
    sc[t] += add;
    __syncthreads();
  }
  int pre = sc[t] - tsum;
  __syncthreads();
  hist[4 * t]     = pre;
  hist[4 * t + 1] = pre + h0;
  hist[4 * t + 2] = pre + h0 + h1;
  hist[4 * t + 3] = pre + h0 + h1 + h2;
  __syncthreads();
  size_t sb = (size_t)c * (NB + 1);
  for (int b = t; b < NB; b += 256) {
    int lo = hist[b];
    segs[sb + b] = lo;
    counts[b * NBLK + c] = hist[b + 1] - lo;
  }
  if (t == 0) segs[sb + NB] = sz;
  __syncthreads();
#pragma unroll
  for (int r = 0; r < 16; ++r) {
    if (key[r] >= 0) {
      int pos = atomicAdd(&hist[key[r]], 1);
      ebuf32[pos] = pk[r];
      ebufd[pos]  = dl[r];
    }
  }
  __syncthreads();
  for (int i = t; i < sz; i += 256) {
    payloadA[cbase + i] = ebuf32[i];
    dlowA[cbase + i]    = ebufd[i];
  }
}

// ---- Pass C: per-bucket assembly + node counting sort; streaming writes ----
__global__ void __launch_bounds__(256)
k_sortb2(const unsigned* __restrict__ payloadA, const unsigned char* __restrict__ dlowA,
         const int* __restrict__ segs, const int* __restrict__ cnts,
         unsigned* __restrict__ payloadB, int* __restrict__ rs,
         float* __restrict__ dis, int N, int NB, int NBLK) {
  __shared__ unsigned ebuf32[SMAX];        // 24 KB
  __shared__ unsigned char ebufd[SMAX];    // 6 KB
  __shared__ int hcnt[128];
  __shared__ int scn[128];
  __shared__ float dgs[128];
  int t = threadIdx.x;
  int b = blockIdx.x;
  if (t < 128) { hcnt[t] = 0; dgs[t] = 1.0f; }
  __syncthreads();
  int beg = cnts[b * NBLK];
  int end = cnts[b * NBLK + NBLK];
  for (int c = t; c < NBLK; c += 256) {
    int rel = cnts[b * NBLK + c] - beg;
    size_t sb = (size_t)c * (NB + 1) + b;
    int s0 = segs[sb], s1 = segs[sb + 1];
    int gsrc = c * CHUNK + s0;
    for (int k = 0; k < s1 - s0; ++k) {
      unsigned p = payloadA[gsrc + k];
      unsigned char d8 = dlowA[gsrc + k];
      ebuf32[rel + k] = p;
      ebufd[rel + k]  = d8;
      atomicAdd(&hcnt[d8], 1);
      atomicAdd(&dgs[d8], edgeW(p));
    }
  }
  __syncthreads();
  int v = (t < 128) ? hcnt[t] : 0;
  if (t < 128) scn[t] = v;
  __syncthreads();
  for (int off = 1; off < 128; off <<= 1) {
    int add = (t < 128 && t >= off) ? scn[t - off] : 0;
    __syncthreads();
    if (t < 128) scn[t] += add;
    __syncthreads();
  }
  int base = b * 128;
  if (t < 128) {
    int st = scn[t] - v;
    hcnt[t] = st;
    rs[base + t] = beg + st;
    int n = base + t;
    if (n < N) dis[n] = rsqrtf(dgs[t]);
  }
  if (t == 0) rs[base + 128] = end;
  __syncthreads();
  int sz = end - beg;
  for (int i = t; i < sz; i += 256) {
    int pos = beg + atomicAdd(&hcnt[ebufd[i]], 1);
    payloadB[pos] = ebuf32[i];
  }
}

__device__ __forceinline__ float blo(unsigned u) { return __uint_as_float(u << 16); }
__device__ __forceinline__ float bhi(unsigned u) { return __uint_as_float(u & 0xffff0000u); }
__device__ __forceinline__ unsigned pack2(float lo, float hi) {
  __hip_bfloat16 l = __float2bfloat16(lo), h = __float2bfloat16(hi);
  unsigned short ul = *reinterpret_cast<unsigned short*>(&l);
  unsigned short uh = *reinterpret_cast<unsigned short*>(&h);
  return (unsigned)ul | ((unsigned)uh << 16);
}

// ---- h1' = (x @ W1) * dis : LDS-staged + register double-buffer (r14, 87us) ----
__global__ void __launch_bounds__(256)
k_gemm1f(const float* __restrict__ x, const float* __restrict__ W1,
         const float* __restrict__ dis, uint4* __restrict__ hb1, int N) {
  __shared__ unsigned xs[4352];   // max(64*65 stage, 4*64*17 overlay) = 17.4 KB
  int t = threadIdx.x;
  int nb = blockIdx.x * 64;
  int r = t & 63;
  int sId = __builtin_amdgcn_readfirstlane(t >> 6);   // wave id 0..3, scalar
  float2 acc[8];
#pragma unroll
  for (int j2 = 0; j2 < 8; ++j2) acc[j2] = make_float2(0.f, 0.f);

  float4 ld0, ld1, ld2, ld3, ld4, ld5, ld6, ld7;
#define G1F_LOAD(c)                                                          \
  do {                                                                       \
    int f;                                                                   \
    f = t;           { int row = f >> 5, sl = f & 31; int n = nb + row;      \
      ld0 = (n < N) ? *reinterpret_cast<const float4*>(x + (size_t)n * F_IN + (c) * 128 + sl * 4) : make_float4(0,0,0,0); } \
    f = t + 256;     { int row = f >> 5, sl = f & 31; int n = nb + row;      \
      ld1 = (n < N) ? *reinterpret_cast<const float4*>(x + (size_t)n * F_IN + (c) * 128 + sl * 4) : make_float4(0,0,0,0); } \
    f = t + 512;     { int row = f >> 5, sl = f & 31; int n = nb + row;      \
      ld2 = (n < N) ? *reinterpret_cast<const float4*>(x + (size_t)n * F_IN + (c) * 128 + sl * 4) : make_float4(0,0,0,0); } \
    f = t + 768;     { int row = f >> 5, sl = f & 31; int n = nb + row;      \
      ld3 = (n < N) ? *reinterpret_cast<const float4*>(x + (size_t)n * F_IN + (c) * 128 + sl * 4) : make_float4(0,0,0,0); } \
    f = t + 1024;    { int row = f >> 5, sl = f & 31; int n = nb + row;      \
      ld4 = (n < N) ? *reinterpret_cast<const float4*>(x + (size_t)n * F_IN + (c) * 128 + sl * 4) : make_float4(0,0,0,0); } \
    f = t + 1280;    { int row = f >> 5, sl = f & 31; int n = nb + row;      \
      ld5 = (n < N) ? *reinterpret_cast<const float4*>(x + (size_t)n * F_IN + (c) * 128 + sl * 4) : make_float4(0,0,0,0); } \
    f = t + 1536;    { int row = f >> 5, sl = f & 31; int n = nb + row;      \
      ld6 = (n < N) ? *reinterpret_cast<const float4*>(x + (size_t)n * F_IN + (c) * 128 + sl * 4) : make_float4(0,0,0,0); } \
    f = t + 1792;    { int row = f >> 5, sl = f & 31; int n = nb + row;      \
      ld7 = (n < N) ? *reinterpret_cast<const float4*>(x + (size_t)n * F_IN + (c) * 128 + sl * 4) : make_float4(0,0,0,0); } \
  } while (0)
#define G1F_STORE()                                                          \
  do {                                                                       \
    int f;                                                                   \
    f = t;        { int row = f >> 5, sl = f & 31; int w = row * 65 + sl * 2; \
      xs[w] = pack2(ld0.x, ld0.y); xs[w + 1] = pack2(ld0.z, ld0.w); }        \
    f = t + 256;  { int row = f >> 5, sl = f & 31; int w = row * 65 + sl * 2; \
      xs[w] = pack2(ld1.x, ld1.y); xs[w + 1] = pack2(ld1.z, ld1.w); }        \
    f = t + 512;  { int row = f >> 5, sl = f & 31; int w = row * 65 + sl * 2; \
      xs[w] = pack2(ld2.x, ld2.y); xs[w + 1] = pack2(ld2.z, ld2.w); }        \
    f = t + 768;  { int row = f >> 5, sl = f & 31; int w = row * 65 + sl * 2; \
      xs[w] = pack2(ld3.x, ld3.y); xs[w + 1] = pack2(ld3.z, ld3.w); }        \
    f = t + 1024; { int row = f >> 5, sl = f & 31; int w = row * 65 + sl * 2; \
      xs[w] = pack2(ld4.x, ld4.y); xs[w + 1] = pack2(ld4.z, ld4.w); }        \
    f = t + 1280; { int row = f >> 5, sl = f & 31; int w = row * 65 + sl * 2; \
      xs[w] = pack2(ld5.x, ld5.y); xs[w + 1] = pack2(ld5.z, ld5.w); }        \
    f = t + 1536; { int row = f >> 5, sl = f & 31; int w = row * 65 + sl * 2; \
      xs[w] = pack2(ld6.x, ld6.y); xs[w + 1] = pack2(ld6.z, ld6.w); }        \
    f = t + 1792; { int row = f >> 5, sl = f & 31; int w = row * 65 + sl * 2; \
      xs[w] = pack2(ld7.x, ld7.y); xs[w + 1] = pack2(ld7.z, ld7.w); }        \
  } while (0)

  G1F_LOAD(0);

#pragma unroll
  for (int c = 0; c < 4; ++c) {
    __syncthreads();
    G1F_STORE();
    if (c < 3) G1F_LOAD(c + 1);
    __syncthreads();
    {
      const unsigned* xcol = &xs[r * 65 + sId * 16];
      const float* wbase = W1 + (size_t)(c * 128 + sId * 32) * HID;
#pragma unroll
      for (int mm = 0; mm < 16; ++mm) {
        unsigned u = xcol[mm];
        float x0 = blo(u), x1 = bhi(u);
        const float* w0 = wbase + mm * 32;
        const float* w1 = w0 + HID;
#pragma unroll
        for (int j2 = 0; j2 < 8; ++j2) {
          float2 p0 = *reinterpret_cast<const float2*>(w0 + 2 * j2);
          float2 p1 = *reinterpret_cast<const float2*>(w1 + 2 * j2);
          acc[j2].x = fmaf(x1, p1.x, fmaf(x0, p0.x, acc[j2].x));
          acc[j2].y = fmaf(x1, p1.y, fmaf(x0, p0.y, acc[j2].y));
        }
      }
    }
  }

  __syncthreads();
  float* ps = reinterpret_cast<float*>(xs);
#pragma unroll
  for (int j2 = 0; j2 < 8; ++j2) {
    ps[(sId * 64 + r) * 17 + 2 * j2]     = acc[j2].x;
    ps[(sId * 64 + r) * 17 + 2 * j2 + 1] = acc[j2].y;
  }
  __syncthreads();
  if (t < 64) {
    int n = nb + t;
    if (n < N) {
      float di = dis[n];
      float o[HID];
#pragma unroll
      for (int j = 0; j < HID; ++j)
        o[j] = (ps[t * 17 + j] + ps[(64 + t) * 17 + j] +
                ps[(128 + t) * 17 + j] + ps[(192 + t) * 17 + j]) * di;
      uint4 w0, w1;
      w0.x = pack2(o[0],  o[1]);  w0.y = pack2(o[2],  o[3]);
      w0.z = pack2(o[4],  o[5]);  w0.w = pack2(o[6],  o[7]);
      w1.x = pack2(o[8],  o[9]);  w1.y = pack2(o[10], o[11]);
      w1.z = pack2(o[12], o[13]); w1.w = pack2(o[14], o[15]);
      hb1[(size_t)n * 2]     = w0;
      hb1[(size_t)n * 2 + 1] = w1;
    }
  }
#undef G1F_LOAD
#undef G1F_STORE
}

// ---- aggregation: EIGHT LANES PER NODE, packed 4B edges, 3-round shfl combine.
//      LAYER1: hb2 = bf16(relu((acc+self)*dis+b1)*dis)
//      LAYER2: fused 16->40 GEMM + log_softmax (lane q: classes [5q,5q+5)) ----
template <int LAYER>
__global__ void __launch_bounds__(256)
k_aggn8(const unsigned* __restrict__ payload, const int* __restrict__ rs,
        const uint4* __restrict__ hb, const float* __restrict__ dis,
        const float* __restrict__ b1, uint4* __restrict__ hb2,
        const float* __restrict__ W2, const float* __restrict__ b2,
        float* __restrict__ out, int N) {
  int tid = blockIdx.x * 256 + threadIdx.x;
  int n = tid >> 3;
  int q = tid & 7;
  if (n >= N) return;
  int e0 = rs[n], e1 = rs[n + 1];
  float a0 = 0, a1 = 0, a2 = 0, a3 = 0, a4 = 0, a5 = 0, a6 = 0, a7 = 0;
  float a8 = 0, a9 = 0, a10 = 0, a11 = 0, a12 = 0, a13 = 0, a14 = 0, a15 = 0;
  for (int e = e0 + q; e < e1; e += 8) {
    unsigned p = payload[e];
    const uint4* row = hb + ((size_t)(p >> 15) * 2);
    uint4 r0 = row[0];
    uint4 r1 = row[1];
    float w = edgeW(p);
    a0  = fmaf(blo(r0.x), w, a0);  a1  = fmaf(bhi(r0.x), w, a1);
    a2  = fmaf(blo(r0.y), w, a2);  a3  = fmaf(bhi(r0.y), w, a3);
    a4  = fmaf(blo(r0.z), w, a4);  a5  = fmaf(bhi(r0.z), w, a5);
    a6  = fmaf(blo(r0.w), w, a6);  a7  = fmaf(bhi(r0.w), w, a7);
    a8  = fmaf(blo(r1.x), w, a8);  a9  = fmaf(bhi(r1.x), w, a9);
    a10 = fmaf(blo(r1.y), w, a10); a11 = fmaf(bhi(r1.y), w, a11);
    a12 = fmaf(blo(r1.z), w, a12); a13 = fmaf(bhi(r1.z), w, a13);
    a14 = fmaf(blo(r1.w), w, a14); a15 = fmaf(bhi(r1.w), w, a15);
  }
#pragma unroll
  for (int m = 1; m <= 4; m <<= 1) {
    a0  += __shfl_xor(a0,  m); a1  += __shfl_xor(a1,  m);
    a2  += __shfl_xor(a2,  m); a3  += __shfl_xor(a3,  m);
    a4  += __shfl_xor(a4,  m); a5  += __shfl_xor(a5,  m);
    a6  += __shfl_xor(a6,  m); a7  += __shfl_xor(a7,  m);
    a8  += __shfl_xor(a8,  m); a9  += __shfl_xor(a9,  m);
    a10 += __shfl_xor(a10, m); a11 += __shfl_xor(a11, m);
    a12 += __shfl_xor(a12, m); a13 += __shfl_xor(a13, m);
    a14 += __shfl_xor(a14, m); a15 += __shfl_xor(a15, m);
  }
  uint4 s0 = hb[(size_t)n * 2];
  uint4 s1 = hb[(size_t)n * 2 + 1];
  float di = dis[n];
  a0  = (a0  + blo(s0.x)) * di;  a1  = (a1  + bhi(s0.x)) * di;
  a2  = (a2  + blo(s0.y)) * di;  a3  = (a3  + bhi(s0.y)) * di;
  a4  = (a4  + blo(s0.z)) * di;  a5  = (a5  + bhi(s0.z)) * di;
  a6  = (a6  + blo(s0.w)) * di;  a7  = (a7  + bhi(s0.w)) * di;
  a8  = (a8  + blo(s1.x)) * di;  a9  = (a9  + bhi(s1.x)) * di;
  a10 = (a10 + blo(s1.y)) * di;  a11 = (a11 + bhi(s1.y)) * di;
  a12 = (a12 + blo(s1.z)) * di;  a13 = (a13 + bhi(s1.z)) * di;
  a14 = (a14 + blo(s1.w)) * di;  a15 = (a15 + bhi(s1.w)) * di;
  if (LAYER == 1) {
    a0  = fmaxf(a0  + b1[0],  0.0f) * di;  a1  = fmaxf(a1  + b1[1],  0.0f) * di;
    a2  = fmaxf(a2  + b1[2],  0.0f) * di;  a3  = fmaxf(a3  + b1[3],  0.0f) * di;
    a4  = fmaxf(a4  + b1[4],  0.0f) * di;  a5  = fmaxf(a5  + b1[5],  0.0f) * di;
    a6  = fmaxf(a6  + b1[6],  0.0f) * di;  a7  = fmaxf(a7  + b1[7],  0.0f) * di;
    a8  = fmaxf(a8  + b1[8],  0.0f) * di;  a9  = fmaxf(a9  + b1[9],  0.0f) * di;
    a10 = fmaxf(a10 + b1[10], 0.0f) * di;  a11 = fmaxf(a11 + b1[11], 0.0f) * di;
    a12 = fmaxf(a12 + b1[12], 0.0f) * di;  a13 = fmaxf(a13 + b1[13], 0.0f) * di;
    a14 = fmaxf(a14 + b1[14], 0.0f) * di;  a15 = fmaxf(a15 + b1[15], 0.0f) * di;
    if (q == 0) {
      uint4 w0;
      w0.x = pack2(a0, a1);  w0.y = pack2(a2,  a3);
      w0.z = pack2(a4, a5);  w0.w = pack2(a6,  a7);
      hb2[(size_t)n * 2] = w0;
    } else if (q == 1) {
      uint4 w1;
      w1.x = pack2(a8,  a9);  w1.y = pack2(a10, a11);
      w1.z = pack2(a12, a13); w1.w = pack2(a14, a15);
      hb2[(size_t)n * 2 + 1] = w1;
    }
  } else {
    float gv[16] = {a0, a1, a2, a3, a4, a5, a6, a7,
                    a8, a9, a10, a11, a12, a13, a14, a15};
    float o[5];
#pragma unroll
    for (int cc = 0; cc < 5; ++cc) o[cc] = b2[q * 5 + cc];
#pragma unroll
    for (int j = 0; j < HID; ++j) {
      float gj = gv[j];
      const float* wr = W2 + j * NCLS + q * 5;
#pragma unroll
      for (int cc = 0; cc < 5; ++cc) o[cc] = fmaf(gj, wr[cc], o[cc]);
    }
    float m = o[0];
#pragma unroll
    for (int cc = 1; cc < 5; ++cc) m = fmaxf(m, o[cc]);
    m = fmaxf(m, __shfl_xor(m, 1));
    m = fmaxf(m, __shfl_xor(m, 2));
    m = fmaxf(m, __shfl_xor(m, 4));
    float ss = 0.0f;
#pragma unroll
    for (int cc = 0; cc < 5; ++cc) ss += expf(o[cc] - m);
    ss += __shfl_xor(ss, 1);
    ss += __shfl_xor(ss, 2);
    ss += __shfl_xor(ss, 4);
    float lse = m + logf(ss);
    float* orow = out + (size_t)n * NCLS + q * 5;
#pragma unroll
    for (int cc = 0; cc < 5; ++cc) orow[cc] = o[cc] - lse;
  }
}

extern "C" void kernel_launch(void* const* d_in, const int* in_sizes, int n_in,
                              void* d_out, int out_size, void* d_ws, size_t ws_size,
                              hipStream_t stream) {
  const float* x  = (const float*)d_in[0];
  const int*   ei = (const int*)d_in[1];
  const float* ew = (const float*)d_in[2];
  const float* W1 = (const float*)d_in[3];
  const float* b1 = (const float*)d_in[4];
  const float* W2 = (const float*)d_in[5];
  const float* b2 = (const float*)d_in[6];
  float* out = (float*)d_out;

  const int N = in_sizes[0] / F_IN;   // 100000
  const int E = in_sizes[2];          // 3200000
  const int* src = ei;
  const int* dst = ei + E;

  const int NB   = (N + 127) >> 7;             // 782 buckets
  const int NBLK = (E + CHUNK - 1) / CHUNK;    // 782 chunks
  const long long SCT = (long long)NB * NBLK + 1;
  const int Npad = (int)((SCT + 1023) & ~1023LL);
  const int nbScan = Npad / 1024;
  const int Nr   = (NB * 128 + 256 + 255) & ~255;
  const size_t SEGSZ = (size_t)NBLK * (NB + 1) + 4;
  const int valid = NB * NBLK;

  // ws layout (4B words): counts[Npad] | bsum[1024] | dis[Nr] | rs[Nr] |
  //   hb1[N*8] | hb2[N*8] | payloadA[E] | dlowA[E/4] | segs[SEGSZ] | payloadB[E]
  int* counts = (int*)d_ws;
  int* bsum   = counts + Npad;
  float* dis  = (float*)(bsum + 1024);
  int* rs     = (int*)(dis + Nr);
  uint4* hb1  = (uint4*)(rs + Nr);
  uint4* hb2  = hb1 + (size_t)N * 2;
  unsigned* payloadA = (unsigned*)(hb2 + (size_t)N * 2);
  unsigned char* dlowA = (unsigned char*)(payloadA + (size_t)E);
  int* segs   = (int*)(dlowA + (((size_t)E + 3) & ~3ull));
  unsigned* payloadB = (unsigned*)(segs + SEGSZ);

  k_scat2<<<NBLK, 256, 0, stream>>>(src, dst, ew, payloadA, dlowA, segs, counts, E, NB, NBLK);
  k_scanA<<<nbScan, 256, 0, stream>>>(counts, bsum, valid);
  k_scanB<<<1, 1024, 0, stream>>>(bsum, nbScan);
  k_scanC<<<nbScan, 256, 0, stream>>>(counts, bsum, valid);
  k_sortb2<<<NB, 256, 0, stream>>>(payloadA, dlowA, segs, counts, payloadB, rs, dis, N, NB, NBLK);
  k_gemm1f<<<(N + 63) / 64, 256, 0, stream>>>(x, W1, dis, hb1, N);
  const int gAgg = (N * 8 + 255) / 256;
  k_aggn8<1><<<gAgg, 256, 0, stream>>>(payloadB, rs, hb1, dis, b1, hb2,
                                       nullptr, nullptr, nullptr, N);
  k_aggn8<2><<<gAgg, 256, 0, stream>>>(payloadB, rs, hb2, dis, nullptr, nullptr,
                                       W2, b2, out, N);
}